// Round 7
// baseline (118.140 us; speedup 1.0000x reference)
//
#include <hip/hip_runtime.h>
#include <math.h>
#include <stdint.h>

#define B_ 16
#define L_ 50
#define LU_ 60
#define KU_ 100
#define DIM_ 60
#define V_ 2000
#define MAXVL_ 10
#define MIN_WL_ 4
#define MAX_WL_ 10
#define NE_ 7            // MAX_WL - MIN_WL + 1
#define IDC_ 3.5f
#define LOG_UNEXT_ (-4.6051701859880913680359829093687f)  // log(0.01)
#define CTXW_ 0.1f

// workspace layout
#define WS_PLP  0                 // pos_lp: B*L*KU = 80000 floats (16B-aligned)
#define WS_BEST_BYTES (80000u * 4u)
#define BEST_STRIDE 8             // 64 B between per-batch atomic slots

#define URP_ 61   // padded LDS stride (odd -> conflict-free strided reads)
#define CWP_ 61
#define TSP_ 12   // transposed DP tile stride (48B: 16B-aligned columns)

// -------------------------------------------------------------------------
// Kernel 1 (fused prep+ctx): per (b,l), 256 threads.
//   - stages unit_repr (padded) + transposed conv_w in LDS
//   - computes its own ku_char_repr rows for uid[l-1..l+1] (prep fused)
//   - char log-softmax row for uid[l], conv, ctx log-softmax
//   - pos_lp = clp + 0.1*ctx_lp  -> ws_plp
//   - blocks 0..59 also emit alignment row r=bl; block 0 zeroes g_best
__global__ __launch_bounds__(256) void ctx_kernel(
    const int* __restrict__ uid,        // (B, L)
    const float* __restrict__ unit_repr,// (KU, DIM)
    const float* __restrict__ aligner_w,// (LU, KU)
    const float* __restrict__ conv_w,   // (DIM, DIM, 3)
    const float* __restrict__ conv_b,   // (DIM,)
    float* __restrict__ ws_plp,         // (B*L, KU)
    float* __restrict__ out_align,      // (LU, KU)
    unsigned long long* __restrict__ g_best)
{
  int bl = blockIdx.x;
  int b = bl / L_, l = bl % L_;
  int t = threadIdx.x;
  __shared__ float s_ur[KU_ * URP_];        // unit_repr, row k at k*61
  __shared__ float s_cw[3 * DIM_ * CWP_];   // conv_w transposed: [(i*3+d)*61+o]
  __shared__ float s_aw[3 * KU_];           // aligner rows for uid[l-1..l+1]
  __shared__ float sx[3 * DIM_];            // ku rows (conv input)
  __shared__ float s_kur[DIM_];             // ku row r (alignment blocks)
  __shared__ float swr[DIM_];               // conv output
  __shared__ float sclp[KU_];               // char logits
  __shared__ float slog[KU_];               // ctx logits
  __shared__ float salg[KU_];               // align logits
  __shared__ float sls[3];                  // logsumexp results

  if (bl == 0 && t < B_) g_best[t * BEST_STRIDE] = 0ull;

  // --- stage weights (float4 global loads)
  const float4* ur4 = (const float4*)unit_repr;
  for (int k = t; k < (KU_ * DIM_) / 4; k += 256) {
    float4 v = ur4[k];
    int i0 = 4 * k;
    s_ur[((i0 + 0) / DIM_) * URP_ + ((i0 + 0) % DIM_)] = v.x;
    s_ur[((i0 + 1) / DIM_) * URP_ + ((i0 + 1) % DIM_)] = v.y;
    s_ur[((i0 + 2) / DIM_) * URP_ + ((i0 + 2) % DIM_)] = v.z;
    s_ur[((i0 + 3) / DIM_) * URP_ + ((i0 + 3) % DIM_)] = v.w;
  }
  const float4* cw4 = (const float4*)conv_w;
  for (int k = t; k < (DIM_ * DIM_ * 3) / 4; k += 256) {
    float4 v = cw4[k];
    int i0 = 4 * k;
    float vv[4] = {v.x, v.y, v.z, v.w};
#pragma unroll
    for (int e = 0; e < 4; ++e) {
      int idx = i0 + e;
      int o = idx / (3 * DIM_), id = idx % (3 * DIM_);
      s_cw[id * CWP_ + o] = vv[e];
    }
  }
  // --- aligner rows for the 3 neighborhood uids (OOB -> zeros, matches SAME pad)
  int ud[3];
#pragma unroll
  for (int d = 0; d < 3; ++d) {
    int ld = l + d - 1;
    ud[d] = (ld >= 0 && ld < L_) ? uid[b * L_ + ld] : -1;
  }
  for (int i = t; i < 3 * KU_; i += 256) {
    int d = i / KU_, k = i - d * KU_;
    s_aw[i] = (ud[d] >= 0) ? aligner_w[ud[d] * KU_ + k] : 0.f;
  }
  __syncthreads();

  // --- P1: ku rows (conv input) + (align blocks) ku row r
  if (t < 3 * DIM_) {
    int d = t / DIM_, c = t - d * DIM_;
    float acc = 0.f;
    for (int k = 0; k < KU_; ++k) acc += s_aw[d * KU_ + k] * s_ur[k * URP_ + c];
    sx[t] = acc;
  } else if (bl < LU_ && t >= 192 && t < 192 + DIM_) {
    int c = t - 192;
    float acc = 0.f;
    for (int k = 0; k < KU_; ++k) acc += aligner_w[bl * KU_ + k] * s_ur[k * URP_ + c];
    s_kur[c] = acc;
  }
  __syncthreads();

  // --- P2: conv (wave0 lanes 0-59) + char logits (threads 64..163)
  if (t < DIM_) {
    float acc = conv_b[t];
    for (int i = 0; i < DIM_; ++i) {
      acc += sx[0 * DIM_ + i] * s_cw[(i * 3 + 0) * CWP_ + t];
      acc += sx[1 * DIM_ + i] * s_cw[(i * 3 + 1) * CWP_ + t];
      acc += sx[2 * DIM_ + i] * s_cw[(i * 3 + 2) * CWP_ + t];
    }
    swr[t] = acc;
  } else if (t >= 64 && t < 64 + KU_) {
    int j = t - 64;
    float acc = 0.f;
    for (int d = 0; d < DIM_; ++d) acc += sx[DIM_ + d] * s_ur[j * URP_ + d];
    sclp[j] = acc;
  }
  __syncthreads();

  // --- P3: ctx logits (t<100) + align logits (threads 128..227)
  if (t < KU_) {
    float acc = 0.f;
    for (int d = 0; d < DIM_; ++d) acc += swr[d] * s_ur[t * URP_ + d];
    slog[t] = acc;
  } else if (bl < LU_ && t >= 128 && t < 128 + KU_) {
    int j = t - 128;
    float acc = 0.f;
    for (int d = 0; d < DIM_; ++d) acc += s_kur[d] * s_ur[j * URP_ + d];
    salg[j] = acc;
  }
  __syncthreads();

  // --- P4: three logsumexp reductions, one per wave (butterfly shuffles)
  {
    int w = t >> 6, lane = t & 63;
    int nred = (bl < LU_) ? 3 : 2;
    if (w < nred) {
      const float* arr = (w == 0) ? sclp : (w == 1) ? slog : salg;
      float v1 = arr[lane];
      float v2 = (lane < KU_ - 64) ? arr[64 + lane] : -1e30f;
      float mx = fmaxf(v1, v2);
#pragma unroll
      for (int off = 32; off > 0; off >>= 1)
        mx = fmaxf(mx, __shfl_xor(mx, off));
      float s = expf(v1 - mx) + ((lane < KU_ - 64) ? expf(v2 - mx) : 0.f);
#pragma unroll
      for (int off = 32; off > 0; off >>= 1)
        s += __shfl_xor(s, off);
      if (lane == 0) sls[w] = mx + logf(s);
    }
  }
  __syncthreads();

  // --- P5: outputs
  if (t < KU_) {
    float pos = (sclp[t] - sls[0]) + CTXW_ * (slog[t] - sls[1]);
    ws_plp[bl * KU_ + t] = pos;
    if (bl < LU_) out_align[bl * KU_ + t] = expf(salg[t] - sls[2]);
  }
}

// -------------------------------------------------------------------------
// Kernel 2: column-major DP on a transposed LDS tile, 2 vocab/thread,
// grid (B*L, 4). NO device-scope fences (round-5 lesson: per-wave
// __threadfence = ~190 us of L2 maintenance on 8-XCD gfx950).
__global__ __launch_bounds__(256) void dp_kernel(
    const int* __restrict__ lengths,
    const int* __restrict__ vocab_ids,      // (V, MAXVL)
    const int* __restrict__ vocab_lengths,  // (V,)
    const float* __restrict__ ws_plp,       // (B*L, KU)
    unsigned long long* __restrict__ g_best)
{
  int bl = blockIdx.x;
  int b = bl / L_, l = bl % L_;
  int len_b = lengths[b];
  int imax = len_b - l;
  if (imax > MAX_WL_) imax = MAX_WL_;
  if (imax < MIN_WL_) return;       // uniform across block

  __shared__ float sT[KU_ * TSP_];  // sT[k*12 + i]; rows >= imax are garbage
  __shared__ unsigned long long swave[4];
  int t = threadIdx.x;
  {
    int n = imax * KU_;
    for (int idx = t; idx < n; idx += 256) {
      int i = idx / KU_, k = idx - i * KU_;
      sT[k * TSP_ + i] = ws_plp[(bl + i) * KU_ + k];
    }
  }
  __syncthreads();

  int v0 = blockIdx.y * 512 + t;    // < 2000 always
  int v1 = v0 + 256;
  bool has1 = (v1 < V_);
  int vid0[MAXVL_], vid1[MAXVL_];
#pragma unroll
  for (int j = 0; j < MAXVL_; ++j) vid0[j] = vocab_ids[v0 * MAXVL_ + j];
  if (has1) {
#pragma unroll
    for (int j = 0; j < MAXVL_; ++j) vid1[j] = vocab_ids[v1 * MAXVL_ + j];
  } else {
#pragma unroll
    for (int j = 0; j < MAXVL_; ++j) vid1[j] = 0;
  }
  int vlen0 = vocab_lengths[v0];
  int vlen1 = has1 ? vocab_lengths[v1] : MIN_WL_;
  bool tail = (imax > 8);           // rows 8,9 needed? (uniform per block)

  float A0[MAXVL_ + 1], A1[MAXVL_ + 1];
  float sv0[NE_], sv1[NE_];
#pragma unroll
  for (int e = 0; e < NE_; ++e) { sv0[e] = 0.f; sv1[e] = 0.f; }
#pragma unroll
  for (int i = 0; i <= MAXVL_; ++i) {
    A0[i] = -IDC_ * (float)i;
    A1[i] = A0[i];
  }

#pragma unroll
  for (int j = 1; j <= MAXVL_; ++j) {
    const float* c0 = &sT[vid0[j - 1] * TSP_];
    const float* c1 = &sT[vid1[j - 1] * TSP_];
    float4 a0 = *(const float4*)(c0);
    float4 m0 = *(const float4*)(c0 + 4);
    float4 a1 = *(const float4*)(c1);
    float4 m1 = *(const float4*)(c1 + 4);
    float2 e0 = make_float2(0.f, 0.f), e1 = make_float2(0.f, 0.f);
    if (tail) {                     // uniform branch; garbage rows never
      e0 = *(const float2*)(c0 + 8);// reach guarded outputs (i<=imax)
      e1 = *(const float2*)(c1 + 8);
    }
    float s0[MAXVL_] = {a0.x, a0.y, a0.z, a0.w, m0.x, m0.y, m0.z, m0.w, e0.x, e0.y};
    float s1[MAXVL_] = {a1.x, a1.y, a1.z, a1.w, m1.x, m1.y, m1.z, m1.w, e1.x, e1.y};
    float B0[MAXVL_ + 1], B1[MAXVL_ + 1];
    B0[0] = -IDC_ * (float)j;
    B1[0] = B0[0];
#pragma unroll
    for (int i = 1; i <= MAXVL_; ++i) {
      B0[i] = fmaxf(A0[i - 1] + s0[i - 1], fmaxf(A0[i], B0[i - 1]) - IDC_);
      B1[i] = fmaxf(A1[i - 1] + s1[i - 1], fmaxf(A1[i], B1[i - 1]) - IDC_);
    }
    if (j == vlen0) {
#pragma unroll
      for (int e = 0; e < NE_; ++e) sv0[e] = B0[MIN_WL_ + e];
    }
    if (j == vlen1) {
#pragma unroll
      for (int e = 0; e < NE_; ++e) sv1[e] = B1[MIN_WL_ + e];
    }
#pragma unroll
    for (int i = 0; i <= MAXVL_; ++i) { A0[i] = B0[i]; A1[i] = B1[i]; }
  }

  unsigned long long bestKey = 0ull;
#pragma unroll
  for (int e = 0; e < NE_; ++e) {
    int i = MIN_WL_ + e;
    if (i <= imax) {
      float unext = (float)(len_b - i) * LOG_UNEXT_;
      unsigned int idx_base = (unsigned int)(l * (NE_ * V_) + e * V_);
      {
        float score = sv0[e] + unext;
        unsigned int u = __float_as_uint(score);
        u = (u & 0x80000000u) ? ~u : (u | 0x80000000u);
        unsigned long long key =
            ((unsigned long long)u << 32) |
            (unsigned long long)(~(idx_base + (unsigned int)v0));
        if (key > bestKey) bestKey = key;
      }
      if (has1) {
        float score = sv1[e] + unext;
        unsigned int u = __float_as_uint(score);
        u = (u & 0x80000000u) ? ~u : (u | 0x80000000u);
        unsigned long long key =
            ((unsigned long long)u << 32) |
            (unsigned long long)(~(idx_base + (unsigned int)v1));
        if (key > bestKey) bestKey = key;
      }
    }
  }

#pragma unroll
  for (int off = 32; off > 0; off >>= 1) {
    unsigned long long o = __shfl_down(bestKey, off);
    if (o > bestKey) bestKey = o;
  }
  int wid = t >> 6;
  if ((t & 63) == 0) swave[wid] = bestKey;
  __syncthreads();
  if (t == 0) {
    unsigned long long k0 = swave[0];
    for (int w = 1; w < 4; ++w)
      if (swave[w] > k0) k0 = swave[w];
    atomicMax(g_best + (size_t)b * BEST_STRIDE, k0);
  }
}

// -------------------------------------------------------------------------
// Kernel 3: decode. Separate launch = implicit device-wide fence (cheap).
__global__ void decode_kernel(const unsigned long long* __restrict__ g_best,
                              float* __restrict__ out)
{
  int t = threadIdx.x;
  if (t < B_) {
    unsigned long long key = g_best[t * BEST_STRIDE];
    unsigned int u = (unsigned int)(key >> 32);
    unsigned int idx = ~((unsigned int)(key & 0xFFFFFFFFull));
    unsigned int bits = (u & 0x80000000u) ? (u & 0x7FFFFFFFu) : ~u;
    float val = __uint_as_float(bits);
    int start = (int)(idx / (NE_ * V_));
    int rem = (int)(idx % (NE_ * V_));
    int e = rem / V_;
    int vv = rem % V_;
    out[t] = (float)start;
    out[B_ + t] = (float)(start + MIN_WL_ + e - 1);
    out[2 * B_ + t] = val;
    out[3 * B_ + t] = (float)vv;
  }
}

// -------------------------------------------------------------------------
extern "C" void kernel_launch(void* const* d_in, const int* in_sizes, int n_in,
                              void* d_out, int out_size, void* d_ws, size_t ws_size,
                              hipStream_t stream)
{
  const int* uid            = (const int*)d_in[0];
  const int* lengths        = (const int*)d_in[1];
  const float* unit_repr    = (const float*)d_in[2];
  const float* aligner_w    = (const float*)d_in[3];
  const float* conv_w       = (const float*)d_in[4];
  const float* conv_b       = (const float*)d_in[5];
  const int* vocab_ids      = (const int*)d_in[6];
  const int* vocab_lengths  = (const int*)d_in[7];
  float* out = (float*)d_out;
  float* ws_f = (float*)d_ws;
  unsigned long long* g_best =
      (unsigned long long*)((char*)d_ws + WS_BEST_BYTES);

  ctx_kernel<<<B_ * L_, 256, 0, stream>>>(uid, unit_repr, aligner_w, conv_w,
                                          conv_b, ws_f + WS_PLP, out + 4 * B_,
                                          g_best);
  dim3 g3(B_ * L_, 4);
  dp_kernel<<<g3, 256, 0, stream>>>(lengths, vocab_ids, vocab_lengths,
                                    ws_f + WS_PLP, g_best);
  decode_kernel<<<1, 64, 0, stream>>>(g_best, out);
}

// Round 8
// 112.998 us; speedup vs baseline: 1.0455x; 1.0455x over previous
//
#include <hip/hip_runtime.h>
#include <math.h>
#include <stdint.h>

#define B_ 16
#define L_ 50
#define LU_ 60
#define KU_ 100
#define DIM_ 60
#define V_ 2000
#define MAXVL_ 10
#define MIN_WL_ 4
#define MAX_WL_ 10
#define NE_ 7            // MAX_WL - MIN_WL + 1
#define IDC_ 3.5f
#define LOG_UNEXT_ (-4.6051701859880913680359829093687f)  // log(0.01)
#define CTXW_ 0.1f
#define NQ_ 13           // l-quads per batch row (13*4 >= 50)

// workspace layout
#define WS_PLP  0                 // pos_lp: B*L*KU = 80000 floats (16B-aligned)
#define WS_BEST_BYTES (80000u * 4u)
#define BEST_STRIDE 8             // 64 B between per-batch atomic slots

#define URP_ 61   // padded LDS stride (odd -> conflict-free strided reads)
#define CWP_ 61
#define TSP_ 12   // transposed DP tile stride (48B: 16B-aligned columns)

// -------------------------------------------------------------------------
// Kernel 1: fused prep+ctx, one block per (b, l-quad) = 16*13 = 208 blocks.
// Stages unit_repr + transposed conv_w ONCE per 4 positions (round-7 ctx was
// per-position: 54 MB of weight staging; this is 3.5 MB).
// Blocks 0..59 additionally emit alignment row r=blockIdx.x.
__global__ __launch_bounds__(256) void ctx_kernel(
    const int* __restrict__ uid,        // (B, L)
    const float* __restrict__ unit_repr,// (KU, DIM)
    const float* __restrict__ aligner_w,// (LU, KU)
    const float* __restrict__ conv_w,   // (DIM, DIM, 3)
    const float* __restrict__ conv_b,   // (DIM,)
    float* __restrict__ ws_plp,         // (B*L, KU)
    float* __restrict__ out_align,      // (LU, KU)
    unsigned long long* __restrict__ g_best)
{
  int blk = blockIdx.x;               // 0..207
  int b = blk / NQ_, q = blk % NQ_;
  int l0 = 4 * q;
  int npos = (l0 + 4 <= L_) ? 4 : (L_ - l0);
  int alr = (blk < LU_) ? blk : -1;   // alignment row handled by this block
  int t = threadIdx.x;

  __shared__ float s_ur[KU_ * URP_];       // unit_repr padded (6100)
  __shared__ float s_cw[3 * DIM_ * CWP_];  // conv_w transposed (10980)
  __shared__ float s_aw[7 * KU_];          // 6 neighborhood aligner rows + align row
  __shared__ float s_kx[7 * DIM_];         // 6 ku rows + align ku row
  __shared__ float swr[4 * DIM_];          // conv outputs
  __shared__ float sclp[4 * KU_];          // char logits per position
  __shared__ float sctx[4 * KU_];          // ctx logits per position
  __shared__ float salg[KU_];              // align logits
  __shared__ float sls[9];                 // 8 pos logsumexps + align

  if (blk == 0 && t < B_) g_best[t * BEST_STRIDE] = 0ull;

  // --- P0: stage weights (float4) + aligner rows
  const float4* ur4 = (const float4*)unit_repr;
  for (int k = t; k < (KU_ * DIM_) / 4; k += 256) {
    float4 v = ur4[k];
    int i0 = 4 * k;
    s_ur[((i0 + 0) / DIM_) * URP_ + ((i0 + 0) % DIM_)] = v.x;
    s_ur[((i0 + 1) / DIM_) * URP_ + ((i0 + 1) % DIM_)] = v.y;
    s_ur[((i0 + 2) / DIM_) * URP_ + ((i0 + 2) % DIM_)] = v.z;
    s_ur[((i0 + 3) / DIM_) * URP_ + ((i0 + 3) % DIM_)] = v.w;
  }
  const float4* cw4 = (const float4*)conv_w;
  for (int k = t; k < (DIM_ * DIM_ * 3) / 4; k += 256) {
    float4 v = cw4[k];
    int i0 = 4 * k;
    float vv[4] = {v.x, v.y, v.z, v.w};
#pragma unroll
    for (int e = 0; e < 4; ++e) {
      int idx = i0 + e;
      int o = idx / (3 * DIM_), id = idx % (3 * DIM_);
      s_cw[id * CWP_ + o] = vv[e];
    }
  }
  for (int i = t; i < 7 * KU_; i += 256) {
    int m = i / KU_, k = i - m * KU_;
    float w = 0.f;
    if (m < 6) {
      int ld = l0 - 1 + m;
      if (ld >= 0 && ld < L_) {
        int u = uid[b * L_ + ld];
        w = aligner_w[u * KU_ + k];
      }
    } else if (alr >= 0) {
      w = aligner_w[alr * KU_ + k];
    }
    s_aw[i] = w;
  }
  __syncthreads();

  // --- P1: ku rows (420 outputs, 100 MACs each)
  for (int idx = t; idx < 7 * DIM_; idx += 256) {
    int m = idx / DIM_, c = idx - m * DIM_;
    float acc = 0.f;
    for (int k = 0; k < KU_; ++k) acc += s_aw[m * KU_ + k] * s_ur[k * URP_ + c];
    s_kx[idx] = acc;
  }
  __syncthreads();

  // --- P2: conv (240) + char logits (400)
  for (int idx = t; idx < 240 + 4 * KU_; idx += 256) {
    if (idx < 240) {
      int p = idx / DIM_, o = idx - p * DIM_;
      float acc = conv_b[o];
      for (int i = 0; i < DIM_; ++i) {
        acc += s_kx[(p + 0) * DIM_ + i] * s_cw[(i * 3 + 0) * CWP_ + o];
        acc += s_kx[(p + 1) * DIM_ + i] * s_cw[(i * 3 + 1) * CWP_ + o];
        acc += s_kx[(p + 2) * DIM_ + i] * s_cw[(i * 3 + 2) * CWP_ + o];
      }
      swr[p * DIM_ + o] = acc;
    } else {
      int r = idx - 240;
      int p = r / KU_, j = r - p * KU_;
      float acc = 0.f;
      for (int d = 0; d < DIM_; ++d) acc += s_kx[(p + 1) * DIM_ + d] * s_ur[j * URP_ + d];
      sclp[r] = acc;
    }
  }
  __syncthreads();

  // --- P3: ctx logits (400) + align logits (100)
  for (int idx = t; idx < 4 * KU_ + KU_; idx += 256) {
    if (idx < 4 * KU_) {
      int p = idx / KU_, j = idx - p * KU_;
      float acc = 0.f;
      for (int d = 0; d < DIM_; ++d) acc += swr[p * DIM_ + d] * s_ur[j * URP_ + d];
      sctx[idx] = acc;
    } else {
      int j = idx - 4 * KU_;
      float acc = 0.f;
      for (int d = 0; d < DIM_; ++d) acc += s_kx[6 * DIM_ + d] * s_ur[j * URP_ + d];
      salg[j] = acc;
    }
  }
  __syncthreads();

  // --- P4: 9 logsumexp reductions (8 groups of 32 lanes, 2 rounds)
  {
    int g = t >> 5, lane = t & 31;
#pragma unroll
    for (int round = 0; round < 2; ++round) {
      int r = round * 8 + g;
      if (r < 9) {
        const float* arr = (r == 8) ? salg
                          : ((r & 1) ? &sctx[(r >> 1) * KU_] : &sclp[(r >> 1) * KU_]);
        float v1 = arr[lane];
        float v2 = arr[32 + lane];
        float v3 = arr[64 + lane];
        float v4 = (lane < KU_ - 96) ? arr[96 + lane] : -1e30f;
        float mx = fmaxf(fmaxf(v1, v2), fmaxf(v3, v4));
#pragma unroll
        for (int off = 16; off > 0; off >>= 1)
          mx = fmaxf(mx, __shfl_xor(mx, off));
        float s = expf(v1 - mx) + expf(v2 - mx) + expf(v3 - mx) +
                  ((lane < KU_ - 96) ? expf(v4 - mx) : 0.f);
#pragma unroll
        for (int off = 16; off > 0; off >>= 1)
          s += __shfl_xor(s, off);
        if (lane == 0) sls[r] = mx + logf(s);
      }
    }
  }
  __syncthreads();

  // --- P5: guarded outputs
  for (int idx = t; idx < 4 * KU_; idx += 256) {
    int p = idx / KU_, j = idx - p * KU_;
    if (p < npos) {
      float pos = (sclp[idx] - sls[2 * p]) + CTXW_ * (sctx[idx] - sls[2 * p + 1]);
      ws_plp[(b * L_ + l0 + p) * KU_ + j] = pos;
    }
  }
  if (alr >= 0 && t < KU_)
    out_align[alr * KU_ + t] = expf(salg[t] - sls[8]);
}

// -------------------------------------------------------------------------
// Kernel 2: column-major DP, transposed LDS tile, 2 vocab/thread,
// grid (B*L, 4). Byte-packed vids + fold-at-capture keep VGPRs low
// (round-7 post-mortem: VGPR=108 -> occupancy 14% -> latency-bound 42.8us).
// NO device-scope fences (round-5: per-wave __threadfence = ~190us).
__global__ __launch_bounds__(256) void dp_kernel(
    const int* __restrict__ lengths,
    const int* __restrict__ vocab_ids,      // (V, MAXVL)
    const int* __restrict__ vocab_lengths,  // (V,)
    const float* __restrict__ ws_plp,       // (B*L, KU)
    unsigned long long* __restrict__ g_best)
{
  int bl = blockIdx.x;
  int b = bl / L_, l = bl % L_;
  int len_b = lengths[b];
  int imax = len_b - l;
  if (imax > MAX_WL_) imax = MAX_WL_;
  if (imax < MIN_WL_) return;       // uniform across block

  __shared__ float sT[KU_ * TSP_];  // sT[k*12 + i]; rows >= imax are garbage
  __shared__ unsigned long long swave[4];
  int t = threadIdx.x;
  {
    int n = imax * KU_;
    for (int idx = t; idx < n; idx += 256) {
      int i = idx / KU_, k = idx - i * KU_;
      sT[k * TSP_ + i] = ws_plp[(bl + i) * KU_ + k];
    }
  }
  __syncthreads();

  int v0 = blockIdx.y * 512 + t;    // < 2000 always
  int v1 = v0 + 256;
  bool has1 = (v1 < V_);
  // byte-pack the 10 char ids (<100) into 3 dwords per vocab entry
  unsigned p0[3] = {0u, 0u, 0u}, p1[3] = {0u, 0u, 0u};
#pragma unroll
  for (int j = 0; j < MAXVL_; ++j)
    p0[j >> 2] |= ((unsigned)vocab_ids[v0 * MAXVL_ + j]) << ((j & 3) * 8);
  if (has1) {
#pragma unroll
    for (int j = 0; j < MAXVL_; ++j)
      p1[j >> 2] |= ((unsigned)vocab_ids[v1 * MAXVL_ + j]) << ((j & 3) * 8);
  }
  int vlen0 = vocab_lengths[v0];
  int vlen1 = has1 ? vocab_lengths[v1] : 0;   // 0 never matches j

  float A0[MAXVL_ + 1], A1[MAXVL_ + 1];
#pragma unroll
  for (int i = 0; i <= MAXVL_; ++i) {
    A0[i] = -IDC_ * (float)i;
    A1[i] = A0[i];
  }
  unsigned long long bestKey = 0ull;

#pragma unroll
  for (int j = 1; j <= MAXVL_; ++j) {
    int k0 = (int)((p0[(j - 1) >> 2] >> (((j - 1) & 3) * 8)) & 0xFFu);
    int k1 = (int)((p1[(j - 1) >> 2] >> (((j - 1) & 3) * 8)) & 0xFFu);
    const float* c0 = &sT[k0 * TSP_];
    const float* c1 = &sT[k1 * TSP_];
    float4 a0 = *(const float4*)(c0);
    float4 m0 = *(const float4*)(c0 + 4);
    float2 e0 = *(const float2*)(c0 + 8);
    float4 a1 = *(const float4*)(c1);
    float4 m1 = *(const float4*)(c1 + 4);
    float2 e1 = *(const float2*)(c1 + 8);
    float s0[MAXVL_] = {a0.x, a0.y, a0.z, a0.w, m0.x, m0.y, m0.z, m0.w, e0.x, e0.y};
    float s1[MAXVL_] = {a1.x, a1.y, a1.z, a1.w, m1.x, m1.y, m1.z, m1.w, e1.x, e1.y};
    float B0[MAXVL_ + 1], B1[MAXVL_ + 1];
    B0[0] = -IDC_ * (float)j;
    B1[0] = B0[0];
#pragma unroll
    for (int i = 1; i <= MAXVL_; ++i) {
      B0[i] = fmaxf(A0[i - 1] + s0[i - 1], fmaxf(A0[i], B0[i - 1]) - IDC_);
      B1[i] = fmaxf(A1[i - 1] + s1[i - 1], fmaxf(A1[i], B1[i - 1]) - IDC_);
    }
    // fold directly at the capture column (no sv[] arrays -> fewer VGPRs)
    if (j == vlen0) {
#pragma unroll
      for (int e = 0; e < NE_; ++e) {
        int i = MIN_WL_ + e;
        if (i <= imax) {    // uniform
          float score = B0[i] + (float)(len_b - i) * LOG_UNEXT_;
          unsigned int idx = (unsigned int)(l * (NE_ * V_) + e * V_ + v0);
          unsigned int u = __float_as_uint(score);
          u = (u & 0x80000000u) ? ~u : (u | 0x80000000u);
          unsigned long long key =
              ((unsigned long long)u << 32) | (unsigned long long)(~idx);
          if (key > bestKey) bestKey = key;
        }
      }
    }
    if (j == vlen1) {       // vlen1=0 when !has1 -> never taken
#pragma unroll
      for (int e = 0; e < NE_; ++e) {
        int i = MIN_WL_ + e;
        if (i <= imax) {
          float score = B1[i] + (float)(len_b - i) * LOG_UNEXT_;
          unsigned int idx = (unsigned int)(l * (NE_ * V_) + e * V_ + v1);
          unsigned int u = __float_as_uint(score);
          u = (u & 0x80000000u) ? ~u : (u | 0x80000000u);
          unsigned long long key =
              ((unsigned long long)u << 32) | (unsigned long long)(~idx);
          if (key > bestKey) bestKey = key;
        }
      }
    }
#pragma unroll
    for (int i = 0; i <= MAXVL_; ++i) { A0[i] = B0[i]; A1[i] = B1[i]; }
  }

#pragma unroll
  for (int off = 32; off > 0; off >>= 1) {
    unsigned long long o = __shfl_down(bestKey, off);
    if (o > bestKey) bestKey = o;
  }
  int wid = t >> 6;
  if ((t & 63) == 0) swave[wid] = bestKey;
  __syncthreads();
  if (t == 0) {
    unsigned long long k0 = swave[0];
    for (int w = 1; w < 4; ++w)
      if (swave[w] > k0) k0 = swave[w];
    atomicMax(g_best + (size_t)b * BEST_STRIDE, k0);
  }
}

// -------------------------------------------------------------------------
// Kernel 3: decode. Separate launch = implicit device-wide fence (cheap).
__global__ void decode_kernel(const unsigned long long* __restrict__ g_best,
                              float* __restrict__ out)
{
  int t = threadIdx.x;
  if (t < B_) {
    unsigned long long key = g_best[t * BEST_STRIDE];
    unsigned int u = (unsigned int)(key >> 32);
    unsigned int idx = ~((unsigned int)(key & 0xFFFFFFFFull));
    unsigned int bits = (u & 0x80000000u) ? (u & 0x7FFFFFFFu) : ~u;
    float val = __uint_as_float(bits);
    int start = (int)(idx / (NE_ * V_));
    int rem = (int)(idx % (NE_ * V_));
    int e = rem / V_;
    int vv = rem % V_;
    out[t] = (float)start;
    out[B_ + t] = (float)(start + MIN_WL_ + e - 1);
    out[2 * B_ + t] = val;
    out[3 * B_ + t] = (float)vv;
  }
}

// -------------------------------------------------------------------------
extern "C" void kernel_launch(void* const* d_in, const int* in_sizes, int n_in,
                              void* d_out, int out_size, void* d_ws, size_t ws_size,
                              hipStream_t stream)
{
  const int* uid            = (const int*)d_in[0];
  const int* lengths        = (const int*)d_in[1];
  const float* unit_repr    = (const float*)d_in[2];
  const float* aligner_w    = (const float*)d_in[3];
  const float* conv_w       = (const float*)d_in[4];
  const float* conv_b       = (const float*)d_in[5];
  const int* vocab_ids      = (const int*)d_in[6];
  const int* vocab_lengths  = (const int*)d_in[7];
  float* out = (float*)d_out;
  float* ws_f = (float*)d_ws;
  unsigned long long* g_best =
      (unsigned long long*)((char*)d_ws + WS_BEST_BYTES);

  ctx_kernel<<<B_ * NQ_, 256, 0, stream>>>(uid, unit_repr, aligner_w, conv_w,
                                           conv_b, ws_f + WS_PLP, out + 4 * B_,
                                           g_best);
  dim3 g3(B_ * L_, 4);
  dp_kernel<<<g3, 256, 0, stream>>>(lengths, vocab_ids, vocab_lengths,
                                    ws_f + WS_PLP, g_best);
  decode_kernel<<<1, 64, 0, stream>>>(g_best, out);
}

// Round 9
// 102.330 us; speedup vs baseline: 1.1545x; 1.1043x over previous
//
#include <hip/hip_runtime.h>
#include <math.h>
#include <stdint.h>

#define B_ 16
#define L_ 50
#define LU_ 60
#define KU_ 100
#define DIM_ 60
#define V_ 2000
#define MAXVL_ 10
#define MIN_WL_ 4
#define MAX_WL_ 10
#define NE_ 7            // MAX_WL - MIN_WL + 1
#define IDC_ 3.5f
#define LOG_UNEXT_ (-4.6051701859880913680359829093687f)  // log(0.01)
#define CTXW_ 0.1f
#define NQ_ 13           // l-quads per batch row (13*4 >= 50)

// workspace layout (bytes)
#define WS_PLP  0                  // pos_lp: B*L*KU = 80000 floats
#define WS_BEST_BYTES (80000u * 4u)       // 320000: 16 padded u64 slots
#define BEST_STRIDE 8              // 64 B between per-batch atomic slots
#define WS_VPACK_BYTES (WS_BEST_BYTES + 1024u)  // 321024 (16B aligned): 2000 int4

#define URP_ 61   // padded LDS stride (odd -> conflict-free strided reads)
#define CWP_ 61
#define TSP_ 12   // transposed DP tile stride (48B: 16B-aligned columns)

// -------------------------------------------------------------------------
// Kernel 1: fused prep+ctx, one block per (b, l-quad) = 208 blocks, plus one
// extra block (blk==208) that counting-sorts vocab by length into vpack
// (int4 per entry: 3 byte-packed vid dwords + (vlen | v<<8)).
// Blocks 0..59 additionally emit alignment row r=blk; block 0 zeroes g_best.
__global__ __launch_bounds__(256) void ctx_kernel(
    const int* __restrict__ uid,        // (B, L)
    const float* __restrict__ unit_repr,// (KU, DIM)
    const float* __restrict__ aligner_w,// (LU, KU)
    const float* __restrict__ conv_w,   // (DIM, DIM, 3)
    const float* __restrict__ conv_b,   // (DIM,)
    const int* __restrict__ vocab_ids,  // (V, MAXVL)
    const int* __restrict__ vocab_lengths, // (V,)
    float* __restrict__ ws_plp,         // (B*L, KU)
    float* __restrict__ out_align,      // (LU, KU)
    unsigned long long* __restrict__ g_best,
    int* __restrict__ vpack)            // (V, int4)
{
  int blk = blockIdx.x;
  int t = threadIdx.x;

  // ---- sort block: counting-sort vocab by vlen, pack ids
  if (blk == B_ * NQ_) {
    __shared__ unsigned cnt[NE_];
    if (t < NE_) cnt[t] = 0u;
    __syncthreads();
    for (int v = t; v < V_; v += 256)
      atomicAdd(&cnt[vocab_lengths[v] - MIN_WL_], 1u);
    __syncthreads();
    if (t == 0) {
      unsigned s = 0;
      for (int e = 0; e < NE_; ++e) { unsigned c = cnt[e]; cnt[e] = s; s += c; }
    }
    __syncthreads();
    for (int v = t; v < V_; v += 256) {
      int vl = vocab_lengths[v];
      unsigned dst = atomicAdd(&cnt[vl - MIN_WL_], 1u);
      unsigned q0 = 0u, q1 = 0u, q2 = 0u;
#pragma unroll
      for (int j = 0; j < 4; ++j) q0 |= ((unsigned)vocab_ids[v * MAXVL_ + j]) << (j * 8);
#pragma unroll
      for (int j = 0; j < 4; ++j) q1 |= ((unsigned)vocab_ids[v * MAXVL_ + 4 + j]) << (j * 8);
#pragma unroll
      for (int j = 0; j < 2; ++j) q2 |= ((unsigned)vocab_ids[v * MAXVL_ + 8 + j]) << (j * 8);
      int4 w;
      w.x = (int)q0; w.y = (int)q1; w.z = (int)q2;
      w.w = (int)((unsigned)vl | ((unsigned)v << 8));
      ((int4*)vpack)[dst] = w;
    }
    return;
  }

  int b = blk / NQ_, q = blk % NQ_;
  int l0 = 4 * q;
  int npos = (l0 + 4 <= L_) ? 4 : (L_ - l0);
  int alr = (blk < LU_) ? blk : -1;

  __shared__ float s_ur[KU_ * URP_];       // unit_repr padded (6100)
  __shared__ float s_cw[3 * DIM_ * CWP_];  // conv_w transposed (10980)
  __shared__ float s_aw[7 * KU_];          // 6 neighborhood aligner rows + align row
  __shared__ float s_kx[7 * DIM_];         // 6 ku rows + align ku row
  __shared__ float swr[4 * DIM_];          // conv outputs
  __shared__ float sclp[4 * KU_];          // char logits per position
  __shared__ float sctx[4 * KU_];          // ctx logits per position
  __shared__ float salg[KU_];              // align logits
  __shared__ float sls[9];                 // 8 pos logsumexps + align

  if (blk == 0 && t < B_) g_best[t * BEST_STRIDE] = 0ull;

  // --- P0: stage weights (float4 global) + aligner rows
  const float4* ur4 = (const float4*)unit_repr;
  for (int k = t; k < (KU_ * DIM_) / 4; k += 256) {
    float4 v = ur4[k];
    int i0 = 4 * k;
    s_ur[((i0 + 0) / DIM_) * URP_ + ((i0 + 0) % DIM_)] = v.x;
    s_ur[((i0 + 1) / DIM_) * URP_ + ((i0 + 1) % DIM_)] = v.y;
    s_ur[((i0 + 2) / DIM_) * URP_ + ((i0 + 2) % DIM_)] = v.z;
    s_ur[((i0 + 3) / DIM_) * URP_ + ((i0 + 3) % DIM_)] = v.w;
  }
  const float4* cw4 = (const float4*)conv_w;
  for (int k = t; k < (DIM_ * DIM_ * 3) / 4; k += 256) {
    float4 v = cw4[k];
    int i0 = 4 * k;
    float vv[4] = {v.x, v.y, v.z, v.w};
#pragma unroll
    for (int e = 0; e < 4; ++e) {
      int idx = i0 + e;
      int o = idx / (3 * DIM_), id = idx % (3 * DIM_);
      s_cw[id * CWP_ + o] = vv[e];
    }
  }
  for (int i = t; i < 7 * KU_; i += 256) {
    int m = i / KU_, k = i - m * KU_;
    float w = 0.f;
    if (m < 6) {
      int ld = l0 - 1 + m;
      if (ld >= 0 && ld < L_) {
        int u = uid[b * L_ + ld];
        w = aligner_w[u * KU_ + k];
      }
    } else if (alr >= 0) {
      w = aligner_w[alr * KU_ + k];
    }
    s_aw[i] = w;
  }
  __syncthreads();

  // --- P1: ku rows (420 outputs, 100 MACs). s_aw rows read as float4 (16B-
  // aligned, lane-uniform-ish broadcast); s_ur stride-61 scalar (conflict-free)
  for (int idx = t; idx < 7 * DIM_; idx += 256) {
    int m = idx / DIM_, c = idx - m * DIM_;
    const float4* aw4 = (const float4*)&s_aw[m * KU_];
    float acc = 0.f;
    for (int k4 = 0; k4 < KU_ / 4; ++k4) {
      float4 a = aw4[k4];
      int k = 4 * k4;
      acc += a.x * s_ur[(k + 0) * URP_ + c];
      acc += a.y * s_ur[(k + 1) * URP_ + c];
      acc += a.z * s_ur[(k + 2) * URP_ + c];
      acc += a.w * s_ur[(k + 3) * URP_ + c];
    }
    s_kx[idx] = acc;
  }
  __syncthreads();

  // --- P2: conv (240) + char logits (400); s_kx/swr rows via float4
  for (int idx = t; idx < 240 + 4 * KU_; idx += 256) {
    if (idx < 240) {
      int p = idx / DIM_, o = idx - p * DIM_;
      const float4* x04 = (const float4*)&s_kx[(p + 0) * DIM_];
      const float4* x14 = (const float4*)&s_kx[(p + 1) * DIM_];
      const float4* x24 = (const float4*)&s_kx[(p + 2) * DIM_];
      float acc = conv_b[o];
      for (int i4 = 0; i4 < DIM_ / 4; ++i4) {
        float4 x0 = x04[i4], x1 = x14[i4], x2 = x24[i4];
        int i = 4 * i4;
        acc += x0.x * s_cw[((i + 0) * 3 + 0) * CWP_ + o];
        acc += x1.x * s_cw[((i + 0) * 3 + 1) * CWP_ + o];
        acc += x2.x * s_cw[((i + 0) * 3 + 2) * CWP_ + o];
        acc += x0.y * s_cw[((i + 1) * 3 + 0) * CWP_ + o];
        acc += x1.y * s_cw[((i + 1) * 3 + 1) * CWP_ + o];
        acc += x2.y * s_cw[((i + 1) * 3 + 2) * CWP_ + o];
        acc += x0.z * s_cw[((i + 2) * 3 + 0) * CWP_ + o];
        acc += x1.z * s_cw[((i + 2) * 3 + 1) * CWP_ + o];
        acc += x2.z * s_cw[((i + 2) * 3 + 2) * CWP_ + o];
        acc += x0.w * s_cw[((i + 3) * 3 + 0) * CWP_ + o];
        acc += x1.w * s_cw[((i + 3) * 3 + 1) * CWP_ + o];
        acc += x2.w * s_cw[((i + 3) * 3 + 2) * CWP_ + o];
      }
      swr[p * DIM_ + o] = acc;
    } else {
      int r = idx - 240;
      int p = r / KU_, j = r - p * KU_;
      const float4* kx4 = (const float4*)&s_kx[(p + 1) * DIM_];
      float acc = 0.f;
      for (int d4 = 0; d4 < DIM_ / 4; ++d4) {
        float4 x = kx4[d4];
        int d = 4 * d4;
        acc += x.x * s_ur[j * URP_ + d + 0];
        acc += x.y * s_ur[j * URP_ + d + 1];
        acc += x.z * s_ur[j * URP_ + d + 2];
        acc += x.w * s_ur[j * URP_ + d + 3];
      }
      sclp[r] = acc;
    }
  }
  __syncthreads();

  // --- P3: ctx logits (400) + align logits (100)
  for (int idx = t; idx < 4 * KU_ + KU_; idx += 256) {
    if (idx < 4 * KU_) {
      int p = idx / KU_, j = idx - p * KU_;
      const float4* w4 = (const float4*)&swr[p * DIM_];
      float acc = 0.f;
      for (int d4 = 0; d4 < DIM_ / 4; ++d4) {
        float4 x = w4[d4];
        int d = 4 * d4;
        acc += x.x * s_ur[j * URP_ + d + 0];
        acc += x.y * s_ur[j * URP_ + d + 1];
        acc += x.z * s_ur[j * URP_ + d + 2];
        acc += x.w * s_ur[j * URP_ + d + 3];
      }
      sctx[idx] = acc;
    } else {
      int j = idx - 4 * KU_;
      const float4* kx4 = (const float4*)&s_kx[6 * DIM_];
      float acc = 0.f;
      for (int d4 = 0; d4 < DIM_ / 4; ++d4) {
        float4 x = kx4[d4];
        int d = 4 * d4;
        acc += x.x * s_ur[j * URP_ + d + 0];
        acc += x.y * s_ur[j * URP_ + d + 1];
        acc += x.z * s_ur[j * URP_ + d + 2];
        acc += x.w * s_ur[j * URP_ + d + 3];
      }
      salg[j] = acc;
    }
  }
  __syncthreads();

  // --- P4: 9 logsumexp reductions (8 groups of 32 lanes, 2 rounds)
  {
    int g = t >> 5, lane = t & 31;
#pragma unroll
    for (int round = 0; round < 2; ++round) {
      int r = round * 8 + g;
      if (r < 9) {
        const float* arr = (r == 8) ? salg
                          : ((r & 1) ? &sctx[(r >> 1) * KU_] : &sclp[(r >> 1) * KU_]);
        float v1 = arr[lane];
        float v2 = arr[32 + lane];
        float v3 = arr[64 + lane];
        float v4 = (lane < KU_ - 96) ? arr[96 + lane] : -1e30f;
        float mx = fmaxf(fmaxf(v1, v2), fmaxf(v3, v4));
#pragma unroll
        for (int off = 16; off > 0; off >>= 1)
          mx = fmaxf(mx, __shfl_xor(mx, off));
        float s = expf(v1 - mx) + expf(v2 - mx) + expf(v3 - mx) +
                  ((lane < KU_ - 96) ? expf(v4 - mx) : 0.f);
#pragma unroll
        for (int off = 16; off > 0; off >>= 1)
          s += __shfl_xor(s, off);
        if (lane == 0) sls[r] = mx + logf(s);
      }
    }
  }
  __syncthreads();

  // --- P5: guarded outputs
  for (int idx = t; idx < 4 * KU_; idx += 256) {
    int p = idx / KU_, j = idx - p * KU_;
    if (p < npos) {
      float pos = (sclp[idx] - sls[2 * p]) + CTXW_ * (sctx[idx] - sls[2 * p + 1]);
      ws_plp[(b * L_ + l0 + p) * KU_ + j] = pos;
    }
  }
  if (alr >= 0 && t < KU_)
    out_align[alr * KU_ + t] = expf(salg[t] - sls[8]);
}

// -------------------------------------------------------------------------
// Kernel 2: column-major DP, transposed LDS tile, 2 vocab/thread from the
// vlen-sorted vpack (adjacent pair -> near-uniform vlen per wave), grid
// (B*L, 4). Columns j > vlen never affect the capture row (deps flow
// forward), so the unrolled j-loop exits at jmax = max(vlen0, vlen1) —
// with sorted pairing most waves skip 0-6 iterations via execz.
// NO device-scope fences (round-5: per-wave __threadfence = ~190us).
__global__ __launch_bounds__(256) void dp_kernel(
    const int* __restrict__ lengths,
    const float* __restrict__ ws_plp,       // (B*L, KU)
    const int* __restrict__ vpack,          // (V, int4) sorted by vlen
    unsigned long long* __restrict__ g_best)
{
  int bl = blockIdx.x;
  int b = bl / L_, l = bl % L_;
  int len_b = lengths[b];
  int imax = len_b - l;
  if (imax > MAX_WL_) imax = MAX_WL_;
  if (imax < MIN_WL_) return;       // uniform across block

  __shared__ float sT[KU_ * TSP_];  // sT[k*12 + i]; rows >= imax are garbage
  __shared__ unsigned long long swave[4];
  int t = threadIdx.x;
  {
    int n = imax * KU_;
    for (int idx = t; idx < n; idx += 256) {
      int i = idx / KU_, k = idx - i * KU_;
      sT[k * TSP_ + i] = ws_plp[(bl + i) * KU_ + k];
    }
  }
  __syncthreads();

  int p = blockIdx.y * 256 + t;     // 0..1023; entries 2p, 2p+1
  const int4* vp4 = (const int4*)vpack;
  int4 w0 = (2 * p < V_) ? vp4[2 * p] : make_int4(0, 0, 0, 0);
  int4 w1 = (2 * p + 1 < V_) ? vp4[2 * p + 1] : make_int4(0, 0, 0, 0);
  unsigned p0[3] = {(unsigned)w0.x, (unsigned)w0.y, (unsigned)w0.z};
  unsigned p1[3] = {(unsigned)w1.x, (unsigned)w1.y, (unsigned)w1.z};
  int vlen0 = (int)((unsigned)w0.w & 0xFFu);      // 0 when invalid
  int vlen1 = (int)((unsigned)w1.w & 0xFFu);
  int v0 = (int)(((unsigned)w0.w) >> 8);
  int v1 = (int)(((unsigned)w1.w) >> 8);
  int jmax = (vlen0 > vlen1) ? vlen0 : vlen1;

  float A0[MAXVL_ + 1], A1[MAXVL_ + 1];
#pragma unroll
  for (int i = 0; i <= MAXVL_; ++i) {
    A0[i] = -IDC_ * (float)i;
    A1[i] = A0[i];
  }
  unsigned long long bestKey = 0ull;

#pragma unroll
  for (int j = 1; j <= MAXVL_; ++j) {
    if (j <= jmax) {                // near-uniform per wave after sort
      int k0 = (int)((p0[(j - 1) >> 2] >> (((j - 1) & 3) * 8)) & 0xFFu);
      int k1 = (int)((p1[(j - 1) >> 2] >> (((j - 1) & 3) * 8)) & 0xFFu);
      const float* c0 = &sT[k0 * TSP_];
      const float* c1 = &sT[k1 * TSP_];
      float4 a0 = *(const float4*)(c0);
      float4 m0 = *(const float4*)(c0 + 4);
      float2 e0 = *(const float2*)(c0 + 8);
      float4 a1 = *(const float4*)(c1);
      float4 m1 = *(const float4*)(c1 + 4);
      float2 e1 = *(const float2*)(c1 + 8);
      float s0[MAXVL_] = {a0.x, a0.y, a0.z, a0.w, m0.x, m0.y, m0.z, m0.w, e0.x, e0.y};
      float s1[MAXVL_] = {a1.x, a1.y, a1.z, a1.w, m1.x, m1.y, m1.z, m1.w, e1.x, e1.y};
      float B0[MAXVL_ + 1], B1[MAXVL_ + 1];
      B0[0] = -IDC_ * (float)j;
      B1[0] = B0[0];
#pragma unroll
      for (int i = 1; i <= MAXVL_; ++i) {
        B0[i] = fmaxf(A0[i - 1] + s0[i - 1], fmaxf(A0[i], B0[i - 1]) - IDC_);
        B1[i] = fmaxf(A1[i - 1] + s1[i - 1], fmaxf(A1[i], B1[i - 1]) - IDC_);
      }
      if (j == vlen0) {
#pragma unroll
        for (int e = 0; e < NE_; ++e) {
          int i = MIN_WL_ + e;
          if (i <= imax) {          // uniform
            float score = B0[i] + (float)(len_b - i) * LOG_UNEXT_;
            unsigned int idx = (unsigned int)(l * (NE_ * V_) + e * V_ + v0);
            unsigned int u = __float_as_uint(score);
            u = (u & 0x80000000u) ? ~u : (u | 0x80000000u);
            unsigned long long key =
                ((unsigned long long)u << 32) | (unsigned long long)(~idx);
            if (key > bestKey) bestKey = key;
          }
        }
      }
      if (j == vlen1) {
#pragma unroll
        for (int e = 0; e < NE_; ++e) {
          int i = MIN_WL_ + e;
          if (i <= imax) {
            float score = B1[i] + (float)(len_b - i) * LOG_UNEXT_;
            unsigned int idx = (unsigned int)(l * (NE_ * V_) + e * V_ + v1);
            unsigned int u = __float_as_uint(score);
            u = (u & 0x80000000u) ? ~u : (u | 0x80000000u);
            unsigned long long key =
                ((unsigned long long)u << 32) | (unsigned long long)(~idx);
            if (key > bestKey) bestKey = key;
          }
        }
      }
#pragma unroll
      for (int i = 0; i <= MAXVL_; ++i) { A0[i] = B0[i]; A1[i] = B1[i]; }
    }
  }

#pragma unroll
  for (int off = 32; off > 0; off >>= 1) {
    unsigned long long o = __shfl_down(bestKey, off);
    if (o > bestKey) bestKey = o;
  }
  int wid = t >> 6;
  if ((t & 63) == 0) swave[wid] = bestKey;
  __syncthreads();
  if (t == 0) {
    unsigned long long k0 = swave[0];
    for (int w = 1; w < 4; ++w)
      if (swave[w] > k0) k0 = swave[w];
    atomicMax(g_best + (size_t)b * BEST_STRIDE, k0);
  }
}

// -------------------------------------------------------------------------
// Kernel 3: decode. Separate launch = implicit device-wide fence (cheap).
__global__ void decode_kernel(const unsigned long long* __restrict__ g_best,
                              float* __restrict__ out)
{
  int t = threadIdx.x;
  if (t < B_) {
    unsigned long long key = g_best[t * BEST_STRIDE];
    unsigned int u = (unsigned int)(key >> 32);
    unsigned int idx = ~((unsigned int)(key & 0xFFFFFFFFull));
    unsigned int bits = (u & 0x80000000u) ? (u & 0x7FFFFFFFu) : ~u;
    float val = __uint_as_float(bits);
    int start = (int)(idx / (NE_ * V_));
    int rem = (int)(idx % (NE_ * V_));
    int e = rem / V_;
    int vv = rem % V_;
    out[t] = (float)start;
    out[B_ + t] = (float)(start + MIN_WL_ + e - 1);
    out[2 * B_ + t] = val;
    out[3 * B_ + t] = (float)vv;
  }
}

// -------------------------------------------------------------------------
extern "C" void kernel_launch(void* const* d_in, const int* in_sizes, int n_in,
                              void* d_out, int out_size, void* d_ws, size_t ws_size,
                              hipStream_t stream)
{
  const int* uid            = (const int*)d_in[0];
  const int* lengths        = (const int*)d_in[1];
  const float* unit_repr    = (const float*)d_in[2];
  const float* aligner_w    = (const float*)d_in[3];
  const float* conv_w       = (const float*)d_in[4];
  const float* conv_b       = (const float*)d_in[5];
  const int* vocab_ids      = (const int*)d_in[6];
  const int* vocab_lengths  = (const int*)d_in[7];
  float* out = (float*)d_out;
  float* ws_f = (float*)d_ws;
  unsigned long long* g_best =
      (unsigned long long*)((char*)d_ws + WS_BEST_BYTES);
  int* vpack = (int*)((char*)d_ws + WS_VPACK_BYTES);

  ctx_kernel<<<B_ * NQ_ + 1, 256, 0, stream>>>(uid, unit_repr, aligner_w,
                                               conv_w, conv_b, vocab_ids,
                                               vocab_lengths, ws_f + WS_PLP,
                                               out + 4 * B_, g_best, vpack);
  dim3 g3(B_ * L_, 4);
  dp_kernel<<<g3, 256, 0, stream>>>(lengths, ws_f + WS_PLP, vpack, g_best);
  decode_kernel<<<1, 64, 0, stream>>>(g_best, out);
}